// Round 1
// baseline (1181.910 us; speedup 1.0000x reference)
//
#include <hip/hip_runtime.h>
#include <stdint.h>

typedef unsigned short u16;
typedef __attribute__((ext_vector_type(4))) float f32x4;
typedef __attribute__((ext_vector_type(8))) u16 u16x8;
typedef __attribute__((ext_vector_type(8))) __bf16 bf16x8;

#define B_ 8
#define S_ 4096
#define D_ 2048
#define O_ 2048
#define M_ 128
#define KTOP_ 256

// ---------- helpers ----------
__device__ __forceinline__ u16 f2bf(float f) {
  unsigned int u = __float_as_uint(f);
  u = (u + 0x7FFFu + ((u >> 16) & 1u)) >> 16;   // RNE; inputs are finite
  return (u16)u;
}

__device__ __forceinline__ void g2l16(const void* g, void* l) {
  __builtin_amdgcn_global_load_lds(
      (const __attribute__((address_space(1))) unsigned int*)g,
      (__attribute__((address_space(3))) unsigned int*)l,
      16, 0, 0);
}

// ---------- 1. fp32 -> bf16 conversion of x ----------
__global__ __launch_bounds__(256) void cvt_bf16(const float* __restrict__ x,
                                                u16* __restrict__ xb) {
  int64_t idx = (int64_t)blockIdx.x * 256 + threadIdx.x;  // one per 8 elems
  int64_t e = idx * 8;
  f32x4 a = *(const f32x4*)(x + e);
  f32x4 b = *(const f32x4*)(x + e + 4);
  u16x8 r;
  r[0] = f2bf(a[0]); r[1] = f2bf(a[1]); r[2] = f2bf(a[2]); r[3] = f2bf(a[3]);
  r[4] = f2bf(b[0]); r[5] = f2bf(b[1]); r[6] = f2bf(b[2]); r[7] = f2bf(b[3]);
  *(u16x8*)(xb + e) = r;
}

// ---------- 2. prompt partial sums (atomicAdd into zeroed ws) ----------
__global__ __launch_bounds__(256) void prompt_sums(const float* __restrict__ x,
                                                   const int* __restrict__ boundaries,
                                                   float* __restrict__ sums) {
  const int b = blockIdx.z, dt = blockIdx.x, sc = blockIdx.y;
  const int d = dt * 256 + threadIdx.x;
  int bclip = min(max(boundaries[b], 0), S_ - 1);
  const int chunk = S_ / 16;  // 256
  int s0 = sc * chunk;
  int s1 = min(s0 + chunk, bclip + 1);
  if (s1 <= s0) return;
  const float* xp = x + (size_t)b * S_ * D_ + (size_t)s0 * D_ + d;
  float acc = 0.f;
  for (int s = s0; s < s1; ++s, xp += D_) acc += *xp;
  atomicAdd(&sums[b * D_ + d], acc);
}

// ---------- 3. finalize agg, exact top-k by rank-count, permute -> active ----------
__global__ __launch_bounds__(512) void topk_mask(const float* __restrict__ sums,
                                                 const int* __restrict__ boundaries,
                                                 const float* __restrict__ bg_mean,
                                                 const int* __restrict__ perm,
                                                 unsigned char* __restrict__ active) {
  const int b = blockIdx.x;
  __shared__ float v[D_];
  int bclip = min(max(boundaries[b], 0), S_ - 1);
  float denom = fmaxf((float)(bclip + 1), 1.0f);
  for (int d = threadIdx.x; d < D_; d += 512)
    v[d] = fabsf(sums[b * D_ + d] / denom - bg_mean[d]);
  __syncthreads();
  for (int d = threadIdx.x; d < D_; d += 512) {
    float my = v[d];
    int cnt = 0;
    for (int j = 0; j < D_; ++j) {
      float o = v[j];
      cnt += (o > my) || (o == my && j < d);
    }
    if (cnt < KTOP_) active[b * D_ + perm[d]] = 1;
  }
}

// ---------- 4. overlap with saved masks, argmax, build final mask ----------
__global__ __launch_bounds__(128) void select_mask(const unsigned char* __restrict__ active,
                                                   const unsigned char* __restrict__ saved,
                                                   unsigned char* __restrict__ final_mask) {
  const int b = blockIdx.x;
  const int m = threadIdx.x;  // 128 threads, one per saved mask
  __shared__ __align__(16) unsigned char act[D_];
  __shared__ int cnts[M_];
  __shared__ int sh_best, sh_rel;
  for (int d = m; d < D_; d += 128) act[d] = active[b * D_ + d];
  __syncthreads();
  const unsigned int* sp = (const unsigned int*)(saved + (size_t)m * D_);
  const unsigned int* ap = (const unsigned int*)act;
  int c = 0;
  for (int i = 0; i < D_ / 4; ++i) c += __popc(sp[i] & ap[i]);  // bytes are 0/1
  cnts[m] = c;
  __syncthreads();
  if (m == 0) {
    int best = cnts[0], bi = 0;
    for (int i = 1; i < M_; ++i)
      if (cnts[i] > best) { best = cnts[i]; bi = i; }
    sh_best = bi;
    // relevant iff best/256 >= 0.3f  <=>  best >= 77 (exact in fp32)
    sh_rel = (best >= 77) ? 1 : 0;
  }
  __syncthreads();
  int bi = sh_best, rel = sh_rel;
  for (int d = m; d < D_; d += 128)
    final_mask[b * D_ + d] = rel ? saved[(size_t)bi * D_ + d] : 0;
}

// ---------- 5. W_eff[b] = W + mask[b] * W_new  -> bf16 ----------
__global__ __launch_bounds__(256) void build_weff(const float* __restrict__ w,
                                                  const float* __restrict__ nw,
                                                  const unsigned char* __restrict__ fmask,
                                                  u16* __restrict__ weff) {
  int idx = blockIdx.x * 256 + threadIdx.x;  // one per 8 elems; O_*D_/8 = 2^19 per batch
  int bb = idx >> 19;
  int rem = (idx & 524287) << 3;  // element offset within [O_*D_]
  int d = rem & (D_ - 1);
  f32x4 w0 = *(const f32x4*)(w + rem);
  f32x4 w1 = *(const f32x4*)(w + rem + 4);
  f32x4 n0 = *(const f32x4*)(nw + rem);
  f32x4 n1 = *(const f32x4*)(nw + rem + 4);
  const unsigned char* mp = fmask + bb * D_ + d;
  u16x8 r;
#pragma unroll
  for (int i = 0; i < 4; ++i) r[i] = f2bf(w0[i] + (mp[i] ? n0[i] : 0.f));
#pragma unroll
  for (int i = 0; i < 4; ++i) r[4 + i] = f2bf(w1[i] + (mp[4 + i] ? n1[i] : 0.f));
  *(u16x8*)(weff + ((size_t)bb << 22) + rem) = r;
}

// ---------- 6. batched bf16 GEMM: out[b] = Xb[b] @ Weff[b]^T + bias ----------
// m97 structure: 128x128 block tile, BK=32, 4 waves (2x2), 4x4 16x16x32 MFMA per wave
__global__ __launch_bounds__(256) void gemm_bt(const u16* __restrict__ X,
                                               const u16* __restrict__ W,
                                               const float* __restrict__ bias,
                                               float* __restrict__ out) {
  __shared__ __align__(16) u16 lA[128 * 32];
  __shared__ __align__(16) u16 lB[128 * 32];
  const int b = blockIdx.z, mt = blockIdx.y, nt = blockIdx.x;
  const int t = threadIdx.x;
  const int wave = t >> 6, lane = t & 63;
  const int wr = (wave >> 1) * 64, wc = (wave & 1) * 64;
  const int q = lane >> 4, lm = lane & 15;

  const u16* Ab = X + (size_t)b * S_ * D_ + (size_t)(mt * 128) * D_;
  const u16* Bb = W + (size_t)b * O_ * D_ + (size_t)(nt * 128) * D_;

  const int r0 = t >> 2;          // staging row 0..63
  const int c0 = (t & 3) * 8;     // staging col (elems)

  f32x4 acc[4][4] = {};

  for (int k0 = 0; k0 < D_; k0 += 32) {
    g2l16(Ab + (size_t)r0 * D_ + k0 + c0, lA + t * 8);
    g2l16(Ab + (size_t)(r0 + 64) * D_ + k0 + c0, lA + (t + 256) * 8);
    g2l16(Bb + (size_t)r0 * D_ + k0 + c0, lB + t * 8);
    g2l16(Bb + (size_t)(r0 + 64) * D_ + k0 + c0, lB + (t + 256) * 8);
    __syncthreads();

    bf16x8 af[4], bf[4];
#pragma unroll
    for (int i = 0; i < 4; ++i)
      af[i] = *(const bf16x8*)(lA + (wr + i * 16 + lm) * 32 + q * 8);
#pragma unroll
    for (int j = 0; j < 4; ++j)
      bf[j] = *(const bf16x8*)(lB + (wc + j * 16 + lm) * 32 + q * 8);
#pragma unroll
    for (int i = 0; i < 4; ++i)
#pragma unroll
      for (int j = 0; j < 4; ++j)
        acc[i][j] = __builtin_amdgcn_mfma_f32_16x16x32_bf16(af[i], bf[j], acc[i][j], 0, 0, 0);
    __syncthreads();
  }

  // epilogue: C/D layout col=lane&15, row=(lane>>4)*4+reg
  const int col0 = nt * 128 + wc + lm;
  const int row0 = mt * 128 + wr + q * 4;
  float bv[4];
#pragma unroll
  for (int j = 0; j < 4; ++j) bv[j] = bias[col0 + j * 16];
#pragma unroll
  for (int i = 0; i < 4; ++i) {
#pragma unroll
    for (int r = 0; r < 4; ++r) {
      const int row = row0 + i * 16 + r;
      float* op = out + (size_t)b * S_ * O_ + (size_t)row * O_;
#pragma unroll
      for (int j = 0; j < 4; ++j) op[col0 + j * 16] = acc[i][j][r] + bv[j];
    }
  }
}

// ---------- launch ----------
extern "C" void kernel_launch(void* const* d_in, const int* in_sizes, int n_in,
                              void* d_out, int out_size, void* d_ws, size_t ws_size,
                              hipStream_t stream) {
  const float* x          = (const float*)d_in[0];
  const int* boundaries   = (const int*)d_in[1];
  const float* weight     = (const float*)d_in[2];
  const float* bias       = (const float*)d_in[3];
  const float* new_weight = (const float*)d_in[4];
  const int* perm         = (const int*)d_in[5];
  const unsigned char* saved = (const unsigned char*)d_in[6];
  const float* bg_mean    = (const float*)d_in[7];
  float* out = (float*)d_out;

  char* ws = (char*)d_ws;
  const size_t off_xb   = 0;                                   // B*S*D bf16 = 128 MB
  const size_t off_weff = off_xb + (size_t)B_ * S_ * D_ * 2;   // B*O*D bf16 = 64 MB
  const size_t off_sums = off_weff + (size_t)B_ * O_ * D_ * 2; // B*D f32 = 64 KB
  const size_t off_act  = off_sums + (size_t)B_ * D_ * 4;      // B*D u8 = 16 KB
  const size_t off_fin  = off_act + (size_t)B_ * D_;           // B*D u8 = 16 KB

  u16* xb   = (u16*)(ws + off_xb);
  u16* weff = (u16*)(ws + off_weff);
  float* sums = (float*)(ws + off_sums);
  unsigned char* act = (unsigned char*)(ws + off_act);
  unsigned char* fin = (unsigned char*)(ws + off_fin);

  // zero the atomic-sum buffer and active mask (ws is poisoned 0xAA)
  hipMemsetAsync(ws + off_sums, 0, (size_t)B_ * D_ * 4 + (size_t)B_ * D_, stream);

  cvt_bf16<<<(B_ * S_ * D_ / 8) / 256, 256, 0, stream>>>(x, xb);
  prompt_sums<<<dim3(D_ / 256, 16, B_), 256, 0, stream>>>(x, boundaries, sums);
  topk_mask<<<B_, 512, 0, stream>>>(sums, boundaries, bg_mean, perm, act);
  select_mask<<<B_, 128, 0, stream>>>(act, saved, fin);
  build_weff<<<(B_ * O_ * D_ / 8) / 256, 256, 0, stream>>>(weight, new_weight, fin, weff);
  gemm_bt<<<dim3(O_ / 128, S_ / 128, B_), 256, 0, stream>>>(xb, weff, bias, out);
}

// Round 2
// 1098.896 us; speedup vs baseline: 1.0755x; 1.0755x over previous
//
#include <hip/hip_runtime.h>
#include <stdint.h>

typedef unsigned short u16;
typedef __attribute__((ext_vector_type(4))) float f32x4;
typedef __attribute__((ext_vector_type(4))) u16 u16x4;
typedef __attribute__((ext_vector_type(8))) u16 u16x8;
typedef __attribute__((ext_vector_type(8))) __bf16 bf16x8;

#define B_ 8
#define S_ 4096
#define D_ 2048
#define O_ 2048
#define M_ 128
#define KTOP_ 256

// ---------- helpers ----------
__device__ __forceinline__ u16 f2bf(float f) {
  unsigned int u = __float_as_uint(f);
  u = (u + 0x7FFFu + ((u >> 16) & 1u)) >> 16;   // RNE; inputs are finite
  return (u16)u;
}

__device__ __forceinline__ void g2l16(const void* g, void* l) {
  __builtin_amdgcn_global_load_lds(
      (const __attribute__((address_space(1))) unsigned int*)g,
      (__attribute__((address_space(3))) unsigned int*)l,
      16, 0, 0);
}

// ---------- 1. fused: x fp32 -> bf16 AND masked prompt partial sums ----------
// grid (D_/1024, S_/64, B_), 256 thr; thread owns 4 consecutive d, 64 rows
__global__ __launch_bounds__(256) void cvt_and_sum(const float* __restrict__ x,
                                                   const int* __restrict__ bnd,
                                                   u16* __restrict__ xb,
                                                   float* __restrict__ sums) {
  const int b = blockIdx.z;
  const int s0 = blockIdx.y * 64;
  const int d = blockIdx.x * 1024 + threadIdx.x * 4;
  const int bclip = min(max(bnd[b], 0), S_ - 1);
  const float* xp = x + (size_t)b * S_ * D_ + (size_t)s0 * D_ + d;
  u16* op = xb + (size_t)b * S_ * D_ + (size_t)s0 * D_ + d;
  // rows s in [s0, s0+64) contribute to the sum iff s <= bclip
  const int smax = min(64, bclip + 1 - s0);
  float a0 = 0.f, a1 = 0.f, a2 = 0.f, a3 = 0.f;
  for (int i = 0; i < 64; ++i) {
    f32x4 v = *(const f32x4*)xp;
    u16x4 r;
    r[0] = f2bf(v[0]); r[1] = f2bf(v[1]); r[2] = f2bf(v[2]); r[3] = f2bf(v[3]);
    *(u16x4*)op = r;
    if (i < smax) { a0 += v[0]; a1 += v[1]; a2 += v[2]; a3 += v[3]; }
    xp += D_; op += D_;
  }
  if (smax > 0) {
    atomicAdd(&sums[b * D_ + d + 0], a0);
    atomicAdd(&sums[b * D_ + d + 1], a1);
    atomicAdd(&sums[b * D_ + d + 2], a2);
    atomicAdd(&sums[b * D_ + d + 3], a3);
  }
}

// ---------- 2. radix-select top-k (exact, JAX tie order), permute -> active ----------
__global__ __launch_bounds__(256) void topk_mask(const float* __restrict__ sums,
                                                 const int* __restrict__ bnd,
                                                 const float* __restrict__ bg_mean,
                                                 const int* __restrict__ perm,
                                                 unsigned char* __restrict__ active) {
  const int b = blockIdx.x;
  __shared__ unsigned int vb[D_];
  __shared__ int hist[256];
  __shared__ int sh_sel, sh_cum;
  const int bclip = min(max(bnd[b], 0), S_ - 1);
  const float denom = (float)(bclip + 1);
  for (int d = threadIdx.x; d < D_; d += 256) {
    float v = fabsf(sums[b * D_ + d] / denom - bg_mean[d]);
    vb[d] = __float_as_uint(v);  // v >= 0 -> uint order == float order
  }
  __syncthreads();
  unsigned int prefix = 0;
  int r = KTOP_;  // remaining rank (1-based from the top)
  for (int byte = 3; byte >= 0; --byte) {
    for (int i = threadIdx.x; i < 256; i += 256) hist[i] = 0;
    __syncthreads();
    const unsigned int shift = byte * 8;
    const unsigned int pmask = (byte == 3) ? 0u : (0xFFFFFFFFu << (shift + 8));
    for (int d = threadIdx.x; d < D_; d += 256) {
      unsigned int v = vb[d];
      if ((v & pmask) == prefix) atomicAdd(&hist[(v >> shift) & 0xFF], 1);
    }
    __syncthreads();
    if (threadIdx.x == 0) {
      int cum = 0, sel = 0;
      for (int v = 255; v >= 0; --v) {
        if (cum + hist[v] >= r) { sel = v; break; }
        cum += hist[v];
      }
      sh_sel = sel; sh_cum = cum;
    }
    __syncthreads();
    prefix |= ((unsigned int)sh_sel) << shift;
    r -= sh_cum;
    __syncthreads();
  }
  const unsigned int T = prefix;  // exact K-th largest; r = # ties to take
  for (int d = threadIdx.x; d < D_; d += 256)
    if (vb[d] > T) active[b * D_ + perm[d]] = 1;
  if (threadIdx.x == 0) {
    int need = r;
    for (int d = 0; d < D_ && need > 0; ++d)
      if (vb[d] == T) { active[b * D_ + perm[d]] = 1; --need; }
  }
}

// ---------- 3. overlap with saved masks, argmax, build final mask ----------
__global__ __launch_bounds__(128) void select_mask(const unsigned char* __restrict__ active,
                                                   const unsigned char* __restrict__ saved,
                                                   unsigned char* __restrict__ final_mask) {
  const int b = blockIdx.x;
  const int m = threadIdx.x;
  __shared__ __align__(16) unsigned char act[D_];
  __shared__ int cnts[M_];
  __shared__ int sh_best, sh_rel;
  for (int d = m; d < D_; d += 128) act[d] = active[b * D_ + d];
  __syncthreads();
  const unsigned int* sp = (const unsigned int*)(saved + (size_t)m * D_);
  const unsigned int* ap = (const unsigned int*)act;
  int c = 0;
  for (int i = 0; i < D_ / 4; ++i) c += __popc(sp[i] & ap[i]);  // bytes are 0/1
  cnts[m] = c;
  __syncthreads();
  if (m == 0) {
    int best = cnts[0], bi = 0;
    for (int i = 1; i < M_; ++i)
      if (cnts[i] > best) { best = cnts[i]; bi = i; }
    sh_best = bi;
    sh_rel = (best >= 77) ? 1 : 0;  // best/256 >= 0.3f exact integer form
  }
  __syncthreads();
  const int bi = sh_best, rel = sh_rel;
  for (int d = m; d < D_; d += 128)
    final_mask[b * D_ + d] = rel ? saved[(size_t)bi * D_ + d] : 0;
}

// ---------- 4. W_eff[b] = W + mask[b] * W_new  -> bf16 ----------
__global__ __launch_bounds__(256) void build_weff(const float* __restrict__ w,
                                                  const float* __restrict__ nw,
                                                  const unsigned char* __restrict__ fmask,
                                                  u16* __restrict__ weff) {
  int idx = blockIdx.x * 256 + threadIdx.x;
  int bb = idx >> 19;
  int rem = (idx & 524287) << 3;
  int d = rem & (D_ - 1);
  f32x4 w0 = *(const f32x4*)(w + rem);
  f32x4 w1 = *(const f32x4*)(w + rem + 4);
  f32x4 n0 = *(const f32x4*)(nw + rem);
  f32x4 n1 = *(const f32x4*)(nw + rem + 4);
  const unsigned char* mp = fmask + bb * D_ + d;
  u16x8 r;
#pragma unroll
  for (int i = 0; i < 4; ++i) r[i] = f2bf(w0[i] + (mp[i] ? n0[i] : 0.f));
#pragma unroll
  for (int i = 0; i < 4; ++i) r[4 + i] = f2bf(w1[i] + (mp[4 + i] ? n1[i] : 0.f));
  *(u16x8*)(weff + ((size_t)bb << 22) + rem) = r;
}

// ---------- 5. batched bf16 GEMM: out[b] = Xb[b] @ Weff[b]^T + bias ----------
// 128x128 tile, BK=32, 4 waves (2x2), 4x4 16x16x32 MFMA per wave.
// 1-D grid, batch-per-XCD swizzle + 4x4 supertiles for L2 locality.
__global__ __launch_bounds__(256) void gemm_bt(const u16* __restrict__ X,
                                               const u16* __restrict__ W,
                                               const float* __restrict__ bias,
                                               float* __restrict__ out) {
  __shared__ __align__(16) u16 lA[128 * 32];
  __shared__ __align__(16) u16 lB[128 * 32];
  const unsigned int gid = blockIdx.x;
  const int b = gid & 7;            // round-robin dispatch -> batch per XCD
  const int t = gid >> 3;           // 0..511 within batch
  const int st = t >> 4, wi = t & 15;
  const int mt = (st & 7) * 4 + (wi & 3);   // 0..31
  const int nt = (st >> 3) * 4 + (wi >> 2); // 0..15
  const int tid = threadIdx.x;
  const int wave = tid >> 6, lane = tid & 63;
  const int wr = (wave >> 1) * 64, wc = (wave & 1) * 64;
  const int q = lane >> 4, lm = lane & 15;

  const u16* Ab = X + (size_t)b * S_ * D_ + (size_t)(mt * 128) * D_;
  const u16* Bb = W + (size_t)b * O_ * D_ + (size_t)(nt * 128) * D_;

  const int r0 = tid >> 2;
  const int c0 = (tid & 3) * 8;

  f32x4 acc[4][4] = {};

  for (int k0 = 0; k0 < D_; k0 += 32) {
    g2l16(Ab + (size_t)r0 * D_ + k0 + c0, lA + tid * 8);
    g2l16(Ab + (size_t)(r0 + 64) * D_ + k0 + c0, lA + (tid + 256) * 8);
    g2l16(Bb + (size_t)r0 * D_ + k0 + c0, lB + tid * 8);
    g2l16(Bb + (size_t)(r0 + 64) * D_ + k0 + c0, lB + (tid + 256) * 8);
    __syncthreads();

    bf16x8 af[4], bf[4];
#pragma unroll
    for (int i = 0; i < 4; ++i)
      af[i] = *(const bf16x8*)(lA + (wr + i * 16 + lm) * 32 + q * 8);
#pragma unroll
    for (int j = 0; j < 4; ++j)
      bf[j] = *(const bf16x8*)(lB + (wc + j * 16 + lm) * 32 + q * 8);
#pragma unroll
    for (int i = 0; i < 4; ++i)
#pragma unroll
      for (int j = 0; j < 4; ++j)
        acc[i][j] = __builtin_amdgcn_mfma_f32_16x16x32_bf16(af[i], bf[j], acc[i][j], 0, 0, 0);
    __syncthreads();
  }

  const int col0 = nt * 128 + wc + lm;
  const int row0 = mt * 128 + wr + q * 4;
  float bv[4];
#pragma unroll
  for (int j = 0; j < 4; ++j) bv[j] = bias[col0 + j * 16];
#pragma unroll
  for (int i = 0; i < 4; ++i) {
#pragma unroll
    for (int r = 0; r < 4; ++r) {
      const int row = row0 + i * 16 + r;
      float* op = out + (size_t)b * S_ * O_ + (size_t)row * O_;
#pragma unroll
      for (int j = 0; j < 4; ++j) op[col0 + j * 16] = acc[i][j][r] + bv[j];
    }
  }
}

// ---------- launch ----------
extern "C" void kernel_launch(void* const* d_in, const int* in_sizes, int n_in,
                              void* d_out, int out_size, void* d_ws, size_t ws_size,
                              hipStream_t stream) {
  const float* x          = (const float*)d_in[0];
  const int* boundaries   = (const int*)d_in[1];
  const float* weight     = (const float*)d_in[2];
  const float* bias       = (const float*)d_in[3];
  const float* new_weight = (const float*)d_in[4];
  const int* perm         = (const int*)d_in[5];
  const unsigned char* saved = (const unsigned char*)d_in[6];
  const float* bg_mean    = (const float*)d_in[7];
  float* out = (float*)d_out;

  char* ws = (char*)d_ws;
  const size_t off_xb   = 0;                                   // 128 MB
  const size_t off_weff = off_xb + (size_t)B_ * S_ * D_ * 2;   // 64 MB
  const size_t off_sums = off_weff + (size_t)B_ * O_ * D_ * 2; // 64 KB
  const size_t off_act  = off_sums + (size_t)B_ * D_ * 4;      // 16 KB
  const size_t off_fin  = off_act + (size_t)B_ * D_;           // 16 KB

  u16* xb   = (u16*)(ws + off_xb);
  u16* weff = (u16*)(ws + off_weff);
  float* sums = (float*)(ws + off_sums);
  unsigned char* act = (unsigned char*)(ws + off_act);
  unsigned char* fin = (unsigned char*)(ws + off_fin);

  hipMemsetAsync(ws + off_sums, 0, (size_t)B_ * D_ * 4 + (size_t)B_ * D_, stream);

  cvt_and_sum<<<dim3(D_ / 1024, S_ / 64, B_), 256, 0, stream>>>(x, boundaries, xb, sums);
  topk_mask<<<B_, 256, 0, stream>>>(sums, boundaries, bg_mean, perm, act);
  select_mask<<<B_, 128, 0, stream>>>(act, saved, fin);
  build_weff<<<(B_ * O_ * D_ / 8) / 256, 256, 0, stream>>>(weight, new_weight, fin, weff);
  gemm_bt<<<B_ * 512, 256, 0, stream>>>(xb, weff, bias, out);
}